// Round 1
// baseline (747.605 us; speedup 1.0000x reference)
//
#include <hip/hip_runtime.h>
#include <hip/hip_bf16.h>

namespace {
constexpr int kN = 100000;   // nodes
constexpr int kE = 3200000;  // edges
constexpr int kD = 256;      // node_dim
constexpr int kH = 64;       // hidden = latent = 64
constexpr int kG = 128;      // graphs

constexpr size_t kAlign = 512;
constexpr size_t align_up(size_t v) { return (v + kAlign - 1) & ~(kAlign - 1); }

constexpr size_t SZ_N_I   = align_up((size_t)kN * 4);
constexpr size_t OFF_CNT  = 0;                          // int[N]  in-degree counts (zeroed)
constexpr size_t OFF_CUR  = OFF_CNT + SZ_N_I;           // int[N]  fill cursors     (zeroed)
constexpr size_t OFF_GCNT = OFF_CUR + SZ_N_I;           // int[G]  graph counts     (zeroed)
constexpr size_t OFF_QRAW = OFF_GCNT + kAlign;          // f32[G*H] pooled pre-W2   (zeroed)
constexpr size_t ZERO_BYTES = OFF_QRAW + align_up((size_t)kG * kH * 4);
constexpr size_t OFF_DINV = ZERO_BYTES;                 // f32[N]
constexpr size_t OFF_ROWP = OFF_DINV + SZ_N_I;          // int[N] CSR row starts
constexpr size_t OFF_BSUM = OFF_ROWP + SZ_N_I;          // int[512] scan block sums
constexpr size_t OFF_BOFF = OFF_BSUM + 4096;            // int[512] scan block offsets
constexpr size_t OFF_REC  = OFF_BOFF + 4096;            // int2[E] CSR records (src, norm)
constexpr size_t OFF_HL   = OFF_REC + align_up((size_t)kE * 8);   // f32[N*H] x@W1
constexpr size_t OFF_H2   = OFF_HL + align_up((size_t)kN * kH * 4); // f32[N*H] relu(conv1)
} // namespace

// ---------- degree histogram over dst ----------
__global__ void k_hist(const int* __restrict__ dst, int* __restrict__ cnt) {
    int e = blockIdx.x * blockDim.x + threadIdx.x;
    if (e < kE) atomicAdd(&cnt[dst[e]], 1);
}

// ---------- per-graph node counts (batch is sorted; LDS-aggregated) ----------
__global__ void k_gcnt(const int* __restrict__ batch, int* __restrict__ gcnt) {
    __shared__ int h[kG];
    int t = threadIdx.x;
    if (t < kG) h[t] = 0;
    __syncthreads();
    for (int i = blockIdx.x * blockDim.x + t; i < kN; i += gridDim.x * blockDim.x)
        atomicAdd(&h[batch[i]], 1);
    __syncthreads();
    if (t < kG && h[t]) atomicAdd(&gcnt[t], h[t]);
}

// ---------- dinv = rsqrt(indeg + 1) ----------
__global__ void k_dinv(const int* __restrict__ cnt, float* __restrict__ dinv) {
    int i = blockIdx.x * blockDim.x + threadIdx.x;
    if (i < kN) dinv[i] = rsqrtf((float)(cnt[i] + 1));
}

// ---------- exclusive scan of counts -> row_ptr (3 kernels) ----------
__global__ void k_scan1(const int* __restrict__ cnt, int* __restrict__ rowp,
                        int* __restrict__ bsum) {
    __shared__ int s[256];
    int t = threadIdx.x;
    int i = blockIdx.x * 256 + t;
    int v = (i < kN) ? cnt[i] : 0;
    s[t] = v;
    __syncthreads();
    for (int off = 1; off < 256; off <<= 1) {
        int add = (t >= off) ? s[t - off] : 0;
        __syncthreads();
        s[t] += add;
        __syncthreads();
    }
    if (i < kN) rowp[i] = s[t] - v;
    if (t == 255) bsum[blockIdx.x] = s[255];
}

__global__ void k_scan2(const int* __restrict__ bsum, int* __restrict__ boff, int nb) {
    __shared__ int s[512];
    int t = threadIdx.x;
    int v = (t < nb) ? bsum[t] : 0;
    s[t] = v;
    __syncthreads();
    for (int off = 1; off < 512; off <<= 1) {
        int add = (t >= off) ? s[t - off] : 0;
        __syncthreads();
        s[t] += add;
        __syncthreads();
    }
    if (t < nb) boff[t] = s[t] - v;
}

__global__ void k_scan3(int* __restrict__ rowp, const int* __restrict__ boff) {
    int i = blockIdx.x * 256 + threadIdx.x;
    if (i < kN) rowp[i] += boff[blockIdx.x];
}

// ---------- CSR fill: rec[pos] = (src, dinv[src]*dinv[dst]) grouped by dst ----------
__global__ void k_fill(const int* __restrict__ src, const int* __restrict__ dst,
                       const float* __restrict__ dinv, const int* __restrict__ rowp,
                       int* __restrict__ cursor, int2* __restrict__ rec) {
    int e = blockIdx.x * blockDim.x + threadIdx.x;
    if (e >= kE) return;
    int s = src[e], d = dst[e];
    float w = dinv[s] * dinv[d];
    int pos = rowp[d] + atomicAdd(&cursor[d], 1);
    rec[pos] = make_int2(s, __float_as_int(w));
}

// ---------- GEMM1: hl[N][64] = x[N][256] @ W1[256][64] (f32 vector, LDS tiled) ----------
__global__ __launch_bounds__(256) void k_gemm1(const float* __restrict__ x,
                                               const float* __restrict__ W1,
                                               float* __restrict__ hl) {
    constexpr int TM = 64;   // nodes per block
    constexpr int KC = 32;   // k-chunk
    __shared__ float xs[TM][36];      // padded stride 36 (16B-aligned, conflict-light)
    __shared__ float ws[KC][kH];
    int t = threadIdx.x;
    int tx = t & 15;        // col group: cols 4*tx .. 4*tx+3
    int ty = t >> 4;        // node group: nodes 4*ty .. 4*ty+3
    int nb = blockIdx.x * TM;
    float acc[4][4] = {};
    for (int k0 = 0; k0 < kD; k0 += KC) {
        // stage x tile: 64 nodes x 32 k = 512 float4, 2 per thread
        #pragma unroll
        for (int j = 0; j < 2; ++j) {
            int id = t * 2 + j;
            int row = id >> 3;
            int c4 = (id & 7) * 4;
            int node = nb + row;
            if (node >= kN) node = kN - 1;   // duplicate-load pad (stores are guarded)
            float4 v = *(const float4*)(x + (size_t)node * kD + k0 + c4);
            *(float4*)&xs[row][c4] = v;
        }
        // stage W1 tile: 32 k x 64 cols = 512 float4, 2 per thread
        #pragma unroll
        for (int j = 0; j < 2; ++j) {
            int id = t * 2 + j;
            int row = id >> 4;
            int c4 = (id & 15) * 4;
            float4 v = *(const float4*)(W1 + (size_t)(k0 + row) * kH + c4);
            *(float4*)&ws[row][c4] = v;
        }
        __syncthreads();
        #pragma unroll
        for (int kk = 0; kk < KC; ++kk) {
            float a0 = xs[ty * 4 + 0][kk];
            float a1 = xs[ty * 4 + 1][kk];
            float a2 = xs[ty * 4 + 2][kk];
            float a3 = xs[ty * 4 + 3][kk];
            float4 b = *(const float4*)&ws[kk][tx * 4];
            acc[0][0] = fmaf(a0, b.x, acc[0][0]); acc[0][1] = fmaf(a0, b.y, acc[0][1]);
            acc[0][2] = fmaf(a0, b.z, acc[0][2]); acc[0][3] = fmaf(a0, b.w, acc[0][3]);
            acc[1][0] = fmaf(a1, b.x, acc[1][0]); acc[1][1] = fmaf(a1, b.y, acc[1][1]);
            acc[1][2] = fmaf(a1, b.z, acc[1][2]); acc[1][3] = fmaf(a1, b.w, acc[1][3]);
            acc[2][0] = fmaf(a2, b.x, acc[2][0]); acc[2][1] = fmaf(a2, b.y, acc[2][1]);
            acc[2][2] = fmaf(a2, b.z, acc[2][2]); acc[2][3] = fmaf(a2, b.w, acc[2][3]);
            acc[3][0] = fmaf(a3, b.x, acc[3][0]); acc[3][1] = fmaf(a3, b.y, acc[3][1]);
            acc[3][2] = fmaf(a3, b.z, acc[3][2]); acc[3][3] = fmaf(a3, b.w, acc[3][3]);
        }
        __syncthreads();
    }
    #pragma unroll
    for (int i = 0; i < 4; ++i) {
        int node = nb + ty * 4 + i;
        if (node < kN) {
            float4 v = make_float4(acc[i][0], acc[i][1], acc[i][2], acc[i][3]);
            *(float4*)&hl[(size_t)node * kH + tx * 4] = v;
        }
    }
}

// ---------- per-node in-edge gather: sum_e norm_e * feat[src_e][lane] ----------
__device__ __forceinline__ float node_gather(int node, int lane,
                                             const int2* __restrict__ rec,
                                             const int* __restrict__ rowp,
                                             const int* __restrict__ cnt,
                                             const float* __restrict__ feat) {
    int base = rowp[node];
    int len = cnt[node];
    float acc = 0.f;
    for (int c0 = 0; c0 < len; c0 += 64) {
        int m = len - c0; if (m > 64) m = 64;
        int2 r = make_int2(0, 0);
        if (lane < m) r = rec[base + c0 + lane];
        #pragma unroll 4
        for (int k = 0; k < m; ++k) {
            int   s = __shfl(r.x, k, 64);
            float w = __int_as_float(__shfl(r.y, k, 64));
            acc = fmaf(w, feat[(size_t)s * kH + lane], acc);
        }
    }
    return acc;
}

// ---------- conv1: h = relu(Ahat @ hl + b1), one wave per node ----------
__global__ __launch_bounds__(256) void k_conv1(const int2* __restrict__ rec,
                                               const int* __restrict__ rowp,
                                               const int* __restrict__ cnt,
                                               const float* __restrict__ dinv,
                                               const float* __restrict__ hl,
                                               const float* __restrict__ b1,
                                               float* __restrict__ h) {
    int lane = threadIdx.x & 63;
    int wid = blockIdx.x * (blockDim.x >> 6) + (threadIdx.x >> 6);
    if (wid >= kN) return;
    float acc = node_gather(wid, lane, rec, rowp, cnt, hl);
    float di = dinv[wid];
    acc = fmaf(hl[(size_t)wid * kH + lane], di * di, acc);   // self-loop
    h[(size_t)wid * kH + lane] = fmaxf(acc + b1[lane], 0.f);
}

// ---------- conv2 fused with pooling: q_raw[g] += Ahat-aggregated h rows ----------
// batch is sorted -> accumulate per-wave running sum, flush at graph boundaries.
__global__ __launch_bounds__(256) void k_pool(const int2* __restrict__ rec,
                                              const int* __restrict__ rowp,
                                              const int* __restrict__ cnt,
                                              const float* __restrict__ dinv,
                                              const float* __restrict__ h,
                                              const int* __restrict__ batch,
                                              float* __restrict__ q_raw) {
    constexpr int CHUNK = 8;
    int lane = threadIdx.x & 63;
    int wid = blockIdx.x * (blockDim.x >> 6) + (threadIdx.x >> 6);
    int n0 = wid * CHUNK;
    if (n0 >= kN) return;
    int n1 = n0 + CHUNK; if (n1 > kN) n1 = kN;
    int gcur = batch[n0];
    float racc = 0.f;
    for (int i = n0; i < n1; ++i) {
        float acc = node_gather(i, lane, rec, rowp, cnt, h);
        float di = dinv[i];
        acc = fmaf(h[(size_t)i * kH + lane], di * di, acc);  // self-loop
        int g = batch[i];
        if (g != gcur) {
            atomicAdd(&q_raw[(size_t)gcur * kH + lane], racc);
            racc = 0.f;
            gcur = g;
        }
        racc += acc;
    }
    atomicAdd(&q_raw[(size_t)gcur * kH + lane], racc);
}

// ---------- head: z_pool = (q_raw/cnt)@W2 + b2 ; decoder MLP ----------
__global__ __launch_bounds__(64) void k_head(const float* __restrict__ q_raw,
                                             const int* __restrict__ gcnt,
                                             const float* __restrict__ W2,
                                             const float* __restrict__ b2,
                                             const float* __restrict__ Wd1,
                                             const float* __restrict__ bd1,
                                             const float* __restrict__ Wd2,
                                             const float* __restrict__ bd2,
                                             float* __restrict__ out) {
    __shared__ float zm[kH], zp[kH], tt[kH];
    int g = blockIdx.x, c = threadIdx.x;
    int cg = gcnt[g];
    float inv = (cg > 0) ? 1.f / (float)cg : 0.f;
    zm[c] = q_raw[(size_t)g * kH + c] * inv;
    __syncthreads();
    float a = b2[c];
    #pragma unroll 8
    for (int k = 0; k < kH; ++k) a = fmaf(zm[k], W2[k * kH + c], a);
    if (cg == 0) a = 0.f;                 // empty graph -> z_pool row = 0 (matches ref)
    out[(size_t)kG * kD + (size_t)g * kH + c] = a;   // z_pool output (after x_hat block)
    zp[c] = a;
    __syncthreads();
    float t = bd1[c];
    #pragma unroll 8
    for (int k = 0; k < kH; ++k) t = fmaf(zp[k], Wd1[k * 64 + c], t);
    tt[c] = fmaxf(t, 0.f);
    __syncthreads();
    #pragma unroll
    for (int j4 = 0; j4 < 4; ++j4) {
        int col = c + j4 * 64;
        float v = bd2[col];
        #pragma unroll 8
        for (int k = 0; k < 64; ++k) v = fmaf(tt[k], Wd2[k * kD + col], v);
        out[(size_t)g * kD + col] = v;    // x_hat output
    }
}

extern "C" void kernel_launch(void* const* d_in, const int* in_sizes, int n_in,
                              void* d_out, int out_size, void* d_ws, size_t ws_size,
                              hipStream_t stream) {
    const float* x    = (const float*)d_in[0];
    const int*   ei   = (const int*)d_in[1];
    const int*   src  = ei;
    const int*   dst  = ei + kE;
    const int*   batch= (const int*)d_in[2];
    const float* W1   = (const float*)d_in[3];
    const float* b1   = (const float*)d_in[4];
    const float* W2   = (const float*)d_in[5];
    const float* b2   = (const float*)d_in[6];
    const float* Wd1  = (const float*)d_in[7];
    const float* bd1  = (const float*)d_in[8];
    const float* Wd2  = (const float*)d_in[9];
    const float* bd2  = (const float*)d_in[10];
    float* out = (float*)d_out;

    char* ws = (char*)d_ws;
    int*   cnt    = (int*)(ws + OFF_CNT);
    int*   cursor = (int*)(ws + OFF_CUR);
    int*   gcnt   = (int*)(ws + OFF_GCNT);
    float* q_raw  = (float*)(ws + OFF_QRAW);
    float* dinv   = (float*)(ws + OFF_DINV);
    int*   rowp   = (int*)(ws + OFF_ROWP);
    int*   bsum   = (int*)(ws + OFF_BSUM);
    int*   boff   = (int*)(ws + OFF_BOFF);
    int2*  rec    = (int2*)(ws + OFF_REC);
    float* hl     = (float*)(ws + OFF_HL);
    float* h      = (float*)(ws + OFF_H2);

    // zero counts / cursors / gcnt / q_raw in one shot
    hipMemsetAsync(d_ws, 0, ZERO_BYTES, stream);

    const int nScanBlocks = (kN + 255) / 256;  // 391

    k_hist<<<(kE + 255) / 256, 256, 0, stream>>>(dst, cnt);
    k_gcnt<<<128, 256, 0, stream>>>(batch, gcnt);
    k_dinv<<<nScanBlocks, 256, 0, stream>>>(cnt, dinv);
    k_scan1<<<nScanBlocks, 256, 0, stream>>>(cnt, rowp, bsum);
    k_scan2<<<1, 512, 0, stream>>>(bsum, boff, nScanBlocks);
    k_scan3<<<nScanBlocks, 256, 0, stream>>>(rowp, boff);
    k_fill<<<(kE + 255) / 256, 256, 0, stream>>>(src, dst, dinv, rowp, cursor, rec);

    k_gemm1<<<(kN + 63) / 64, 256, 0, stream>>>(x, W1, hl);

    k_conv1<<<(kN + 3) / 4, 256, 0, stream>>>(rec, rowp, cnt, dinv, hl, b1, h);

    const int nPoolWaves = (kN + 7) / 8;
    k_pool<<<(nPoolWaves + 3) / 4, 256, 0, stream>>>(rec, rowp, cnt, dinv, h, batch, q_raw);

    k_head<<<kG, 64, 0, stream>>>(q_raw, gcnt, W2, b2, Wd1, bd1, Wd2, bd2, out);
}